// Round 12
// baseline (151.673 us; speedup 1.0000x reference)
//
#include <hip/hip_runtime.h>
#include <cstddef>
#include <cstdint>

#define EPSBN 1e-5f
constexpr int B_ = 4, N_ = 2048, K_ = 20;

typedef __attribute__((ext_vector_type(8))) _Float16 half8v;
typedef __attribute__((ext_vector_type(4))) float f32x4;
typedef const __attribute__((address_space(1))) unsigned int* gas_t;
typedef __attribute__((address_space(3))) unsigned int* las_t;

// batch-XCD swizzle: block B -> (batch, local) with B&7 = XCD slot, batch b on slots {2b,2b+1}
__device__ __forceinline__ void swz_batch(int B, int& b, int& local) {
    b = (B & 7) >> 1;
    local = ((B >> 3) << 1) | (B & 1);
}

// ---------------- fused weight prep (layers 1-3 conv + w4 cast) ----------------

__device__ __forceinline__ void prep_conv(const float* __restrict__ W, _Float16* __restrict__ W2h,
                                          int O, int C, int i) {
    int o = i / C, c = i - o * C;
    float a = W[o * 2 * C + c];
    float d = W[o * 2 * C + C + c] - a;
    W2h[(size_t)o * C + c] = (_Float16)a;
    W2h[(size_t)(O + o) * C + c] = (_Float16)d;
}

__global__ void k_prep_all(const float* __restrict__ w1, const float* __restrict__ w2,
                           const float* __restrict__ w3, const float* __restrict__ w4,
                           _Float16* __restrict__ W2h1, _Float16* __restrict__ W2h2,
                           _Float16* __restrict__ W2h3, _Float16* __restrict__ w4h) {
    int i = blockIdx.x * 256 + threadIdx.x;
    if (i < 8192) { prep_conv(w1, W2h1, 128, 64, i); return; }
    i -= 8192;
    if (i < 32768) { prep_conv(w2, W2h2, 256, 128, i); return; }
    i -= 32768;
    if (i < 131072) { prep_conv(w3, W2h3, 512, 256, i); return; }
    i -= 131072;
    if (i < 983040) w4h[i] = (_Float16)w4[i];
}

// ---------------- generic MFMA GEMM: out(fp16) = A (8192 x K, stride sa) @ Bw^T ----------------
// BM x 128 tile; 4 waves x ((BM/2) x 64); global_load_lds staging, XOR-swizzled LDS,
// single-buffer (r4/r5/r7: pipelining & in-GEMM transforms all neutral-to-negative).
// r12: BM=64 for ALL layer GEMMs -- doubles grid -> 3-4 blocks/CU demand (24KB LDS, 3
// resident) so cross-block overlap (m114) hides the per-K-step barrier drain.  G3/G4 were
// stuck at 2 blocks/CU (90% stall, MfmaUtil 10.5%); B-panel L2 re-read x2 is ~7us of
// 35TB/s L2 BW -- cheap vs the stall.
template<bool STATS, int BM>
__global__ __launch_bounds__(256, 3)
void k_gemm(const _Float16* __restrict__ A, int sa,
            const _Float16* __restrict__ Bw, int K,
            _Float16* __restrict__ outp, int so,
            float* __restrict__ psum, float* __restrict__ psq) {
    constexpr int MI = BM / 32;
    __shared__ __align__(16) _Float16 Als[BM * 64];
    __shared__ __align__(16) _Float16 Bls[128 * 64];
    const int tid = threadIdx.x, lane = tid & 63, w = tid >> 6;
    int bsw, lsw;
    swz_batch(blockIdx.x, bsw, lsw);
    constexpr int TPB = 2048 / BM;
    const int m0 = (bsw * TPB + lsw) * BM;
    const int n0 = blockIdx.y * 128;
    const int wr = (w >> 1) * (BM / 2), wc = (w & 1) * 64;

    f32x4 acc[MI][4];
#pragma unroll
    for (int i = 0; i < MI; ++i)
#pragma unroll
        for (int j = 0; j < 4; ++j) acc[i][j] = (f32x4){0.f, 0.f, 0.f, 0.f};

    int srb[4], scb[4];
#pragma unroll
    for (int j = 0; j < 4; ++j) {
        int idx = w * 256 + j * 64 + lane;
        srb[j] = idx >> 3;
        scb[j] = ((idx & 7) ^ (srb[j] & 7)) * 8;
    }
    int sra[MI], sca[MI];
#pragma unroll
    for (int j = 0; j < MI; ++j) {
        int idx = w * (MI * 64) + j * 64 + lane;
        sra[j] = idx >> 3;
        sca[j] = ((idx & 7) ^ (sra[j] & 7)) * 8;
    }
    int aoff[MI][2], boff[4][2];
#pragma unroll
    for (int i = 0; i < MI; ++i) {
        int ra = wr + i * 16 + (lane & 15);
#pragma unroll
        for (int t = 0; t < 2; ++t)
            aoff[i][t] = ra * 64 + ((((lane >> 4) + t * 4) ^ (ra & 7)) * 8);
    }
#pragma unroll
    for (int j = 0; j < 4; ++j) {
        int rb = wc + j * 16 + (lane & 15);
#pragma unroll
        for (int t = 0; t < 2; ++t)
            boff[j][t] = rb * 64 + ((((lane >> 4) + t * 4) ^ (rb & 7)) * 8);
    }

    for (int c0 = 0; c0 < K; c0 += 64) {
#pragma unroll
        for (int j = 0; j < MI; ++j) {
            const _Float16* ga = &A[(size_t)(m0 + sra[j]) * sa + c0 + sca[j]];
            __builtin_amdgcn_global_load_lds((gas_t)(const void*)ga,
                                             (las_t)(void*)&Als[(w * MI * 64 + j * 64) * 8], 16, 0, 0);
        }
#pragma unroll
        for (int j = 0; j < 4; ++j) {
            const _Float16* gb = &Bw[(size_t)(n0 + srb[j]) * K + c0 + scb[j]];
            __builtin_amdgcn_global_load_lds((gas_t)(const void*)gb,
                                             (las_t)(void*)&Bls[(w * 256 + j * 64) * 8], 16, 0, 0);
        }
        __syncthreads();
#pragma unroll
        for (int t = 0; t < 2; ++t) {
            half8v a[MI], b[4];
#pragma unroll
            for (int i = 0; i < MI; ++i) a[i] = *(const half8v*)&Als[aoff[i][t]];
#pragma unroll
            for (int j = 0; j < 4; ++j) b[j] = *(const half8v*)&Bls[boff[j][t]];
#pragma unroll
            for (int i = 0; i < MI; ++i)
#pragma unroll
                for (int j = 0; j < 4; ++j)
                    acc[i][j] = __builtin_amdgcn_mfma_f32_16x16x32_f16(a[i], b[j], acc[i][j], 0, 0, 0);
        }
        __syncthreads();
    }
#pragma unroll
    for (int i = 0; i < MI; ++i)
#pragma unroll
        for (int j = 0; j < 4; ++j)
#pragma unroll
            for (int e = 0; e < 4; ++e) {
                int row = m0 + wr + i * 16 + (lane >> 4) * 4 + e;
                int col = n0 + wc + j * 16 + (lane & 15);
                outp[(size_t)row * so + col] = (_Float16)acc[i][j][e];
            }
    if constexpr (STATS) {
        int slice = blockIdx.x & 63;
#pragma unroll
        for (int j = 0; j < 4; ++j) {
            float s = 0.f, q = 0.f;
#pragma unroll
            for (int i = 0; i < MI; ++i)
#pragma unroll
                for (int e = 0; e < 4; ++e) {
                    float v = acc[i][j][e];
                    s += v; q += v * v;
                }
            s += __shfl_xor(s, 16); s += __shfl_xor(s, 32);
            q += __shfl_xor(q, 16); q += __shfl_xor(q, 32);
            if ((lane >> 4) == 0) {
                int col = n0 + wc + j * 16 + lane;
                atomicAdd(&psum[slice * 1024 + col], s);
                atomicAdd(&psq[slice * 1024 + col], q);
            }
        }
    }
}

// ---------------- layer-0: fused dense (C=3) + gather-reduce + BN stats ----------------
__global__ __launch_bounds__(256)
void k_gather0(const float* __restrict__ x, const float* __restrict__ w0,
               const int* __restrict__ nidx, const float* __restrict__ g,
               _Float16* __restrict__ exth,
               float* __restrict__ psum, float* __restrict__ psq) {
    constexpr int O = 64, VPT = 8, P = 32;
    __shared__ float s_red[P * O];
    __shared__ float q_red[P * O];
    const int tid = threadIdx.x;
    const int pl = tid / VPT, v = tid % VPT;
    int bsw, local;
    swz_batch(blockIdx.x, bsw, local);
    const int bbase = bsw * N_;
    const int p = bbase + local * P + pl;
    float wa[8][3], wd[8][3], sg[8];
#pragma unroll
    for (int e = 0; e < 8; ++e) {
        int o = v * 8 + e;
        float a0 = w0[o * 6], a1 = w0[o * 6 + 1], a2 = w0[o * 6 + 2];
        wa[e][0] = a0; wa[e][1] = a1; wa[e][2] = a2;
        wd[e][0] = w0[o * 6 + 3] - a0;
        wd[e][1] = w0[o * 6 + 4] - a1;
        wd[e][2] = w0[o * 6 + 5] - a2;
        sg[e] = (g[o] >= 0.f) ? 1.f : -1.f;
    }
    float mx[8], sm[8], sq[8];
#pragma unroll
    for (int e = 0; e < 8; ++e) { mx[e] = -3.4e38f; sm[e] = 0.f; sq[e] = 0.f; }
    const int* np = nidx + p * K_;
#pragma unroll 4
    for (int k = 0; k < K_; ++k) {
        int j = bbase + np[k];
        float x0 = x[j * 3], x1 = x[j * 3 + 1], x2 = x[j * 3 + 2];
#pragma unroll
        for (int e = 0; e < 8; ++e) {
            float f = wa[e][0] * x0 + wa[e][1] * x1 + wa[e][2] * x2;
            mx[e] = fmaxf(mx[e], f * sg[e]);
            sm[e] += f;
            sq[e] += f * f;
        }
    }
    float xp0 = x[p * 3], xp1 = x[p * 3 + 1], xp2 = x[p * 3 + 2];
    const float Kf = (float)K_;
    half8v exo;
#pragma unroll
    for (int e = 0; e < 8; ++e) {
        float zf = wd[e][0] * xp0 + wd[e][1] * xp1 + wd[e][2] * xp2;
        exo[e] = (_Float16)(sg[e] * mx[e] + zf);
        s_red[pl * O + v * 8 + e] = sm[e] + Kf * zf;
        q_red[pl * O + v * 8 + e] = sq[e] + 2.f * zf * sm[e] + Kf * zf * zf;
    }
    *(half8v*)&exth[(size_t)p * O + v * 8] = exo;
    __syncthreads();
    int slice = blockIdx.x & 63;
    for (int ch = tid; ch < O; ch += 256) {
        float s = 0.f, q = 0.f;
#pragma unroll
        for (int pp = 0; pp < P; ++pp) { s += s_red[pp * O + ch]; q += q_red[pp * O + ch]; }
        atomicAdd(&psum[slice * 1024 + ch], s);
        atomicAdd(&psq[slice * 1024 + ch], q);
    }
}

// ---------------- gather-reduce + fused BN stats (single extremum, batch-XCD-swizzled) ----------------
template<int O>
__global__ __launch_bounds__(256)
void k_gather(const _Float16* __restrict__ Z, const int* __restrict__ nidx,
              const float* __restrict__ g,
              _Float16* __restrict__ exth,
              float* __restrict__ psum, float* __restrict__ psq) {
    constexpr int VPT = O / 8, P = 256 / VPT;
    __shared__ float s_red[P * O];
    __shared__ float q_red[P * O];
    const int tid = threadIdx.x;
    const int pl = tid / VPT, v = tid % VPT;
    int bsw, local;
    swz_batch(blockIdx.x, bsw, local);
    const int bbase = bsw * N_;
    const int p = bbase + local * P + pl;
    float sg[8];
#pragma unroll
    for (int e = 0; e < 8; ++e) sg[e] = (g[v * 8 + e] >= 0.f) ? 1.f : -1.f;
    float mx[8], sm[8], sq[8];
#pragma unroll
    for (int e = 0; e < 8; ++e) { mx[e] = -3.4e38f; sm[e] = 0.f; sq[e] = 0.f; }
    const int* np = nidx + p * K_;
#pragma unroll 4
    for (int k = 0; k < K_; ++k) {
        int j = np[k];
        half8v z = *(const half8v*)&Z[(size_t)(bbase + j) * (2 * O) + v * 8];
#pragma unroll
        for (int e = 0; e < 8; ++e) {
            float f = (float)z[e];
            mx[e] = fmaxf(mx[e], f * sg[e]);
            sm[e] += f;
            sq[e] += f * f;
        }
    }
    half8v zd = *(const half8v*)&Z[(size_t)p * (2 * O) + O + v * 8];
    const float Kf = (float)K_;
    half8v exo;
#pragma unroll
    for (int e = 0; e < 8; ++e) {
        float zf = (float)zd[e];
        exo[e] = (_Float16)(sg[e] * mx[e] + zf);
        s_red[pl * O + v * 8 + e] = sm[e] + Kf * zf;
        q_red[pl * O + v * 8 + e] = sq[e] + 2.f * zf * sm[e] + Kf * zf * zf;
    }
    *(half8v*)&exth[(size_t)p * O + v * 8] = exo;
    __syncthreads();
    int slice = blockIdx.x & 63;
    for (int ch = tid; ch < O; ch += 256) {
        float s = 0.f, q = 0.f;
#pragma unroll
        for (int pp = 0; pp < P; ++pp) { s += s_red[pp * O + ch]; q += q_red[pp * O + ch]; }
        atomicAdd(&psum[slice * 1024 + ch], s);
        atomicAdd(&psq[slice * 1024 + ch], q);
    }
}

// ---------------- fused finalize + BN-apply (consumer-side finalize, r9/r11-verified) ----------------
template<int O>
__global__ __launch_bounds__(256)
void k_bnfin(const _Float16* __restrict__ exth,
             const float* __restrict__ psum, const float* __restrict__ psq,
             const float* __restrict__ g, const float* __restrict__ b, float cntInv,
             _Float16* __restrict__ cath, int coff) {
    constexpr int NCT = O / 64;                      // channel tiles
    __shared__ float part_s[64][4];
    __shared__ float part_q[64][4];
    __shared__ float scale_s[64], shift_s[64];
    const int tid = threadIdx.x;
    const int ct = blockIdx.x % NCT;
    const int ptile = blockIdx.x / NCT;              // [0,64)
    int bsw, local;
    swz_batch(ptile, bsw, local);                    // local in [0,16)
    const int ch0 = ct * 64;
    {   // phase 1: per-channel slice reduction (4 threads/channel, 16 slices each)
        int lc = tid >> 2, q = tid & 3;
        int ch = ch0 + lc;
        float s = 0.f, qq = 0.f;
        for (int i = q * 16; i < q * 16 + 16; ++i) {
            s += psum[i * 1024 + ch];
            qq += psq[i * 1024 + ch];
        }
        part_s[lc][q] = s; part_q[lc][q] = qq;
    }
    __syncthreads();
    if ((tid & 3) == 0) {
        int lc = tid >> 2;
        float s = part_s[lc][0] + part_s[lc][1] + part_s[lc][2] + part_s[lc][3];
        float qq = part_q[lc][0] + part_q[lc][1] + part_q[lc][2] + part_q[lc][3];
        float m = s * cntInv;
        float v = qq * cntInv - m * m;
        float sc = g[ch0 + lc] * rsqrtf(fmaxf(v, 0.f) + EPSBN);
        scale_s[lc] = sc;
        shift_s[lc] = b[ch0 + lc] - m * sc;
    }
    __syncthreads();
    // phase 2: apply to 128 points x 64 channels
    const int pbase = bsw * N_ + local * 128;
#pragma unroll
    for (int r = 0; r < 4; ++r) {
        int idx = r * 256 + tid;
        int ptl = idx >> 3;                          // [0,128)
        int cb = (idx & 7) * 8;                      // [0,64) in steps of 8
        int p = pbase + ptl;
        half8v hx = *(const half8v*)&exth[(size_t)p * O + ch0 + cb];
        half8v rr;
#pragma unroll
        for (int e = 0; e < 8; ++e) {
            float y = scale_s[cb + e] * (float)hx[e] + shift_s[cb + e];
            rr[e] = (_Float16)(y > 0.f ? y : 0.2f * y);
        }
        *(half8v*)&cath[(size_t)p * 960 + coff + ch0 + cb] = rr;
    }
}

// ---------------- BN+lrelu on Y4 -> fo transposed + pool partials (+in-kernel finalize) ----------------
__global__ __launch_bounds__(256)
void k_feats_out(const _Float16* __restrict__ Y4,
                 const float* __restrict__ psum, const float* __restrict__ psq,
                 const float* __restrict__ g, const float* __restrict__ bv,
                 float* __restrict__ fo,
                 float* __restrict__ pmax, float* __restrict__ psumn) {
    __shared__ float tile[64][65];
    __shared__ float part_s[64][4];
    __shared__ float part_q[64][4];
    __shared__ float scale_s[64], shift_s[64];
    const int tid = threadIdx.x;
    // decode: slot = id&7 -> b = slot>>1, parity = slot&1; nx chosen so (nx>>1)&1 == parity
    const int id = blockIdx.x;
    const int b = (id & 7) >> 1, par = id & 1;
    const int local = id >> 3;                       // [0,256)
    const int cy = local >> 4;                       // [0,16) c-tile
    const int k = local & 15;
    const int nx = ((k >> 1) << 2) | (par << 1) | (k & 1);   // [0,32), slot-parity matched
    const int n0 = nx * 64, c0 = cy * 64;
    // ---- phase 0: finalize BN scale/shift for this 64-channel tile ----
    {
        int lc = tid >> 2, q = tid & 3;
        int ch = c0 + lc;
        float s = 0.f, qq = 0.f;
        for (int i = q * 16; i < q * 16 + 16; ++i) {
            s += psum[i * 1024 + ch];
            qq += psq[i * 1024 + ch];
        }
        part_s[lc][q] = s; part_q[lc][q] = qq;
    }
    __syncthreads();
    if ((tid & 3) == 0) {
        int lc = tid >> 2;
        const float cntInv = 1.f / (B_ * N_);
        float s = part_s[lc][0] + part_s[lc][1] + part_s[lc][2] + part_s[lc][3];
        float qq = part_q[lc][0] + part_q[lc][1] + part_q[lc][2] + part_q[lc][3];
        float m = s * cntInv;
        float v = qq * cntInv - m * m;
        float sc = g[c0 + lc] * rsqrtf(fmaxf(v, 0.f) + EPSBN);
        scale_s[lc] = sc;
        shift_s[lc] = bv[c0 + lc] - m * sc;
    }
    __syncthreads();
    // ---- phase 1: vectorized load + BN + lrelu into LDS transpose tile ----
#pragma unroll
    for (int r = 0; r < 2; ++r) {
        int idx = r * 256 + tid;                 // 512 half8 chunks = 64n x 8 c-groups
        int nl = idx >> 3;
        int c8 = (idx & 7) * 8;
        half8v h = *(const half8v*)&Y4[((size_t)(b * N_ + n0 + nl)) * 1024 + c0 + c8];
#pragma unroll
        for (int e = 0; e < 8; ++e) {
            float y = scale_s[c8 + e] * (float)h[e] + shift_s[c8 + e];
            tile[nl][c8 + e] = y > 0.f ? y : 0.2f * y;
        }
    }
    __syncthreads();
    // ---- phase 2: transposed float4 stores + pool partials ----
#pragma unroll
    for (int r = 0; r < 4; ++r) {
        int idx = r * 256 + tid;                 // 1024 float4 chunks = 64c x 16 n-groups
        int cl = idx >> 4;
        int n4 = (idx & 15) * 4;
        float4 v;
        v.x = tile[n4 + 0][cl];
        v.y = tile[n4 + 1][cl];
        v.z = tile[n4 + 2][cl];
        v.w = tile[n4 + 3][cl];
        *(float4*)&fo[((size_t)(b * 1024 + c0 + cl)) * N_ + n0 + n4] = v;
        float mx = fmaxf(fmaxf(v.x, v.y), fmaxf(v.z, v.w));
        float sm = v.x + v.y + v.z + v.w;
#pragma unroll
        for (int d = 1; d < 16; d <<= 1) {       // reduce the 16-lane group covering 64 n
            mx = fmaxf(mx, __shfl_xor(mx, d));
            sm += __shfl_xor(sm, d);
        }
        if ((tid & 15) == 0) {
            int bc = (b << 10) + c0 + cl;
            pmax[(size_t)bc * 32 + nx] = mx;
            psumn[(size_t)bc * 32 + nx] = sm;
        }
    }
}

// final pool: per (b,c) reduce 32 tile-partials -> z0 (B,2048) = [max | mean]
__global__ void k_pool2(const float* __restrict__ pmax, const float* __restrict__ psumn,
                        float* __restrict__ z0) {
    int bc = blockIdx.x * 8 + (threadIdx.x >> 5);
    int lane = threadIdx.x & 31;
    float mx = pmax[(size_t)bc * 32 + lane];
    float s  = psumn[(size_t)bc * 32 + lane];
#pragma unroll
    for (int d = 1; d < 32; d <<= 1) {
        mx = fmaxf(mx, __shfl_xor(mx, d));
        s += __shfl_xor(s, d);
    }
    if (lane == 0) {
        int b = bc >> 10, c = bc & 1023;
        z0[b * 2048 + c] = mx;
        z0[b * 2048 + 1024 + c] = s * (1.f / N_);
    }
}

// ---------------- FC: one wave per (batch, output) dot product; optional fused batch-BN+lrelu ----------------
__global__ void k_fc(const float* __restrict__ zin, const float* __restrict__ W,
                     const float* __restrict__ bias,
                     const float* __restrict__ gg, const float* __restrict__ gb,
                     int C, int O, float* __restrict__ zout) {
    __shared__ float sh4[4];
    const int b = threadIdx.x >> 6;
    const int lane = threadIdx.x & 63;
    const int o = blockIdx.x;
    const float* wr = W + (size_t)o * C;
    const float* zr = zin + b * C;
    float s = 0.f;
    for (int c = lane * 4; c < C; c += 256) {
        const float4 wv = *(const float4*)&wr[c];
        const float4 zv = *(const float4*)&zr[c];
        s += wv.x * zv.x + wv.y * zv.y + wv.z * zv.z + wv.w * zv.w;
    }
    s += __shfl_xor(s, 1);
    s += __shfl_xor(s, 2);
    s += __shfl_xor(s, 4);
    s += __shfl_xor(s, 8);
    s += __shfl_xor(s, 16);
    s += __shfl_xor(s, 32);
    if (!gg) {
        if (lane == 0) zout[b * O + o] = s + (bias ? bias[o] : 0.f);
        return;
    }
    if (lane == 0) sh4[b] = s + (bias ? bias[o] : 0.f);
    __syncthreads();
    if (threadIdx.x == 0) {
        float v0 = sh4[0], v1 = sh4[1], v2 = sh4[2], v3 = sh4[3];
        float m = 0.25f * (v0 + v1 + v2 + v3);
        float d0 = v0 - m, d1 = v1 - m, d2 = v2 - m, d3 = v3 - m;
        float var = 0.25f * (d0 * d0 + d1 * d1 + d2 * d2 + d3 * d3);
        float sc = gg[o] * rsqrtf(var + EPSBN);
        float shv = gb[o];
        float r0 = sc * d0 + shv, r1 = sc * d1 + shv, r2 = sc * d2 + shv, r3 = sc * d3 + shv;
        zout[o]         = r0 > 0.f ? r0 : 0.2f * r0;
        zout[O + o]     = r1 > 0.f ? r1 : 0.2f * r1;
        zout[2 * O + o] = r2 > 0.f ? r2 : 0.2f * r2;
        zout[3 * O + o] = r3 > 0.f ? r3 : 0.2f * r3;
    }
}

// ---------------- launch ----------------

extern "C" void kernel_launch(void* const* d_in, const int* in_sizes, int n_in,
                              void* d_out, int out_size, void* d_ws, size_t ws_size,
                              hipStream_t stream) {
    const float* x    = (const float*)d_in[0];
    const int*   nidx = (const int*)d_in[1];
    const float* w[5]  = {(const float*)d_in[2], (const float*)d_in[5], (const float*)d_in[8],
                          (const float*)d_in[11], (const float*)d_in[14]};
    const float* g[5]  = {(const float*)d_in[3], (const float*)d_in[6], (const float*)d_in[9],
                          (const float*)d_in[12], (const float*)d_in[15]};
    const float* bb[5] = {(const float*)d_in[4], (const float*)d_in[7], (const float*)d_in[10],
                          (const float*)d_in[13], (const float*)d_in[16]};
    const float* lw1 = (const float*)d_in[17];
    const float* g6  = (const float*)d_in[18];
    const float* b6  = (const float*)d_in[19];
    const float* lw2 = (const float*)d_in[20];
    const float* lb2 = (const float*)d_in[21];
    const float* g7  = (const float*)d_in[22];
    const float* b7  = (const float*)d_in[23];
    const float* lw3 = (const float*)d_in[24];
    const float* lb3 = (const float*)d_in[25];

    float* out = (float*)d_out;
    float* fo  = out + 1024;              // feats (B,1024,N)

    uint8_t* base8 = (uint8_t*)d_ws;
    size_t off = 0;
    auto alloc = [&](size_t bytes) -> void* {
        void* r = base8 + off;
        off += (bytes + 255) & ~(size_t)255;
        return r;
    };
    _Float16* cath = (_Float16*)alloc((size_t)B_ * N_ * 960 * 2);   // 15.7 MB
    _Float16* Z    = (_Float16*)alloc((size_t)8192 * 1024 * 2);     // 16.8 MB
    _Float16* exth = (_Float16*)alloc((size_t)8192 * 512 * 2);      // 8.4 MB
    _Float16* Y4   = (_Float16*)alloc((size_t)8192 * 1024 * 2);     // 16.8 MB
    _Float16* W2h1 = (_Float16*)alloc((size_t)256 * 64 * 2);
    _Float16* W2h2 = (_Float16*)alloc((size_t)512 * 128 * 2);
    _Float16* W2h3 = (_Float16*)alloc((size_t)1024 * 256 * 2);
    _Float16* w4h  = (_Float16*)alloc((size_t)1024 * 960 * 2);
    float* psumall = (float*)alloc((size_t)5 * 131072 * 4);         // 2.6 MB, 5 regions
    float* pmax  = (float*)alloc((size_t)4096 * 32 * 4);            // 512 KB
    float* psumn = (float*)alloc((size_t)4096 * 32 * 4);            // 512 KB
    float* z0    = (float*)alloc(8192 * 4);
    float* z1    = (float*)alloc(4096 * 4);
    float* z2    = (float*)alloc(2048 * 4);
    (void)ws_size; (void)in_sizes; (void)n_in; (void)out_size;

    auto psumR = [&](int r) { return psumall + (size_t)r * 131072; };
    auto psqR  = [&](int r) { return psumall + (size_t)r * 131072 + 65536; };

    // one upfront zero of all stat regions + one fused weight-prep launch
    hipMemsetAsync(psumall, 0, (size_t)5 * 131072 * 4, stream);
    k_prep_all<<<(8192 + 32768 + 131072 + 983040 + 255) / 256, 256, 0, stream>>>(
        w[1], w[2], w[3], w[4], W2h1, W2h2, W2h3, w4h);

    const float invK = 1.f / (B_ * N_ * K_);

    // ---- layer 0 (C=3 -> O=64): fused dense + gather, then fused finalize+BN ----
    k_gather0<<<256, 256, 0, stream>>>(x, w[0], nidx, g[0], exth, psumR(0), psqR(0));
    k_bnfin<64><<<64, 256, 0, stream>>>(exth, psumR(0), psqR(0), g[0], bb[0], invK, cath, 0);

    // ---- layers 1-3: dense MFMA GEMM (BM=64, 3 blocks/CU) + fused gather + finalize+BN ----
    k_gemm<false, 64><<<dim3(128, 2), 256, 0, stream>>>(cath + 0, 960, W2h1, 64,
                                                        Z, 256, nullptr, nullptr);
    k_gather<128><<<512, 256, 0, stream>>>(Z, nidx, g[1], exth, psumR(1), psqR(1));
    k_bnfin<128><<<128, 256, 0, stream>>>(exth, psumR(1), psqR(1), g[1], bb[1], invK, cath, 64);

    k_gemm<false, 64><<<dim3(128, 4), 256, 0, stream>>>(cath + 64, 960, W2h2, 128,
                                                        Z, 512, nullptr, nullptr);
    k_gather<256><<<1024, 256, 0, stream>>>(Z, nidx, g[2], exth, psumR(2), psqR(2));
    k_bnfin<256><<<256, 256, 0, stream>>>(exth, psumR(2), psqR(2), g[2], bb[2], invK, cath, 192);

    k_gemm<false, 64><<<dim3(128, 8), 256, 0, stream>>>(cath + 192, 960, W2h3, 256,
                                                        Z, 1024, nullptr, nullptr);
    k_gather<512><<<2048, 256, 0, stream>>>(Z, nidx, g[3], exth, psumR(3), psqR(3));
    k_bnfin<512><<<512, 256, 0, stream>>>(exth, psumR(3), psqR(3), g[3], bb[3], invK, cath, 448);

    // ---- feats = lrelu(bn(w4 @ cat)); finalize fused into feats_out's phase 0 ----
    k_gemm<true, 64><<<dim3(128, 8), 256, 0, stream>>>(cath, 960, w4h, 960, Y4, 1024,
                                                       psumR(4), psqR(4));
    k_feats_out<<<2048, 256, 0, stream>>>(Y4, psumR(4), psqR(4), g[4], bb[4], fo, pmax, psumn);
    k_pool2<<<512, 256, 0, stream>>>(pmax, psumn, z0);

    // ---- FC head (BN fused into FC blocks) ----
    k_fc<<<1024, 256, 0, stream>>>(z0, lw1, nullptr, g6, b6, 2048, 1024, z1);
    k_fc<<<512, 256, 0, stream>>>(z1, lw2, lb2, g7, b7, 1024, 512, z2);
    k_fc<<<256, 256, 0, stream>>>(z2, lw3, lb3, nullptr, nullptr, 512, 256, out);
}

// Round 13
// 145.754 us; speedup vs baseline: 1.0406x; 1.0406x over previous
//
#include <hip/hip_runtime.h>
#include <cstddef>
#include <cstdint>

#define EPSBN 1e-5f
constexpr int B_ = 4, N_ = 2048, K_ = 20;

typedef __attribute__((ext_vector_type(8))) _Float16 half8v;
typedef __attribute__((ext_vector_type(4))) float f32x4;
typedef const __attribute__((address_space(1))) unsigned int* gas_t;
typedef __attribute__((address_space(3))) unsigned int* las_t;

// batch-XCD swizzle: block B -> (batch, local) with B&7 = XCD slot, batch b on slots {2b,2b+1}
__device__ __forceinline__ void swz_batch(int B, int& b, int& local) {
    b = (B & 7) >> 1;
    local = ((B >> 3) << 1) | (B & 1);
}

// ---------------- fused weight prep (layers 1-3 conv + w4 cast) ----------------

__device__ __forceinline__ void prep_conv(const float* __restrict__ W, _Float16* __restrict__ W2h,
                                          int O, int C, int i) {
    int o = i / C, c = i - o * C;
    float a = W[o * 2 * C + c];
    float d = W[o * 2 * C + C + c] - a;
    W2h[(size_t)o * C + c] = (_Float16)a;
    W2h[(size_t)(O + o) * C + c] = (_Float16)d;
}

__global__ void k_prep_all(const float* __restrict__ w1, const float* __restrict__ w2,
                           const float* __restrict__ w3, const float* __restrict__ w4,
                           _Float16* __restrict__ W2h1, _Float16* __restrict__ W2h2,
                           _Float16* __restrict__ W2h3, _Float16* __restrict__ w4h) {
    int i = blockIdx.x * 256 + threadIdx.x;
    if (i < 8192) { prep_conv(w1, W2h1, 128, 64, i); return; }
    i -= 8192;
    if (i < 32768) { prep_conv(w2, W2h2, 256, 128, i); return; }
    i -= 32768;
    if (i < 131072) { prep_conv(w3, W2h3, 512, 256, i); return; }
    i -= 131072;
    if (i < 983040) w4h[i] = (_Float16)w4[i];
}

// ---------------- generic MFMA GEMM: out(fp16) = A (8192 x K, stride sa) @ Bw^T ----------------
// BM x 128 tile; 4 waves x ((BM/2) x 64); global_load_lds staging, XOR-swizzled LDS,
// single-buffer.  Tile ledger (r4/r5/r7/r12): 128x128@2blk/CU is optimal for the big
// K>=256 GEMMs (BM=64 doubles B-staging+barriers: +5us); BM=64 pays only where CU
// coverage is fractional (G1: 0.5->1 blk/CU; G2: 1->2 blk/CU with a small L2-resident
// B panel).  Pipelining/dbuf/in-GEMM transforms: all neutral-to-negative.
template<bool STATS, int BM>
__global__ __launch_bounds__(256, 3)
void k_gemm(const _Float16* __restrict__ A, int sa,
            const _Float16* __restrict__ Bw, int K,
            _Float16* __restrict__ outp, int so,
            float* __restrict__ psum, float* __restrict__ psq) {
    constexpr int MI = BM / 32;
    __shared__ __align__(16) _Float16 Als[BM * 64];
    __shared__ __align__(16) _Float16 Bls[128 * 64];
    const int tid = threadIdx.x, lane = tid & 63, w = tid >> 6;
    int bsw, lsw;
    swz_batch(blockIdx.x, bsw, lsw);
    constexpr int TPB = 2048 / BM;
    const int m0 = (bsw * TPB + lsw) * BM;
    const int n0 = blockIdx.y * 128;
    const int wr = (w >> 1) * (BM / 2), wc = (w & 1) * 64;

    f32x4 acc[MI][4];
#pragma unroll
    for (int i = 0; i < MI; ++i)
#pragma unroll
        for (int j = 0; j < 4; ++j) acc[i][j] = (f32x4){0.f, 0.f, 0.f, 0.f};

    int srb[4], scb[4];
#pragma unroll
    for (int j = 0; j < 4; ++j) {
        int idx = w * 256 + j * 64 + lane;
        srb[j] = idx >> 3;
        scb[j] = ((idx & 7) ^ (srb[j] & 7)) * 8;
    }
    int sra[MI], sca[MI];
#pragma unroll
    for (int j = 0; j < MI; ++j) {
        int idx = w * (MI * 64) + j * 64 + lane;
        sra[j] = idx >> 3;
        sca[j] = ((idx & 7) ^ (sra[j] & 7)) * 8;
    }
    int aoff[MI][2], boff[4][2];
#pragma unroll
    for (int i = 0; i < MI; ++i) {
        int ra = wr + i * 16 + (lane & 15);
#pragma unroll
        for (int t = 0; t < 2; ++t)
            aoff[i][t] = ra * 64 + ((((lane >> 4) + t * 4) ^ (ra & 7)) * 8);
    }
#pragma unroll
    for (int j = 0; j < 4; ++j) {
        int rb = wc + j * 16 + (lane & 15);
#pragma unroll
        for (int t = 0; t < 2; ++t)
            boff[j][t] = rb * 64 + ((((lane >> 4) + t * 4) ^ (rb & 7)) * 8);
    }

    for (int c0 = 0; c0 < K; c0 += 64) {
#pragma unroll
        for (int j = 0; j < MI; ++j) {
            const _Float16* ga = &A[(size_t)(m0 + sra[j]) * sa + c0 + sca[j]];
            __builtin_amdgcn_global_load_lds((gas_t)(const void*)ga,
                                             (las_t)(void*)&Als[(w * MI * 64 + j * 64) * 8], 16, 0, 0);
        }
#pragma unroll
        for (int j = 0; j < 4; ++j) {
            const _Float16* gb = &Bw[(size_t)(n0 + srb[j]) * K + c0 + scb[j]];
            __builtin_amdgcn_global_load_lds((gas_t)(const void*)gb,
                                             (las_t)(void*)&Bls[(w * 256 + j * 64) * 8], 16, 0, 0);
        }
        __syncthreads();
#pragma unroll
        for (int t = 0; t < 2; ++t) {
            half8v a[MI], b[4];
#pragma unroll
            for (int i = 0; i < MI; ++i) a[i] = *(const half8v*)&Als[aoff[i][t]];
#pragma unroll
            for (int j = 0; j < 4; ++j) b[j] = *(const half8v*)&Bls[boff[j][t]];
#pragma unroll
            for (int i = 0; i < MI; ++i)
#pragma unroll
                for (int j = 0; j < 4; ++j)
                    acc[i][j] = __builtin_amdgcn_mfma_f32_16x16x32_f16(a[i], b[j], acc[i][j], 0, 0, 0);
        }
        __syncthreads();
    }
#pragma unroll
    for (int i = 0; i < MI; ++i)
#pragma unroll
        for (int j = 0; j < 4; ++j)
#pragma unroll
            for (int e = 0; e < 4; ++e) {
                int row = m0 + wr + i * 16 + (lane >> 4) * 4 + e;
                int col = n0 + wc + j * 16 + (lane & 15);
                outp[(size_t)row * so + col] = (_Float16)acc[i][j][e];
            }
    if constexpr (STATS) {
        int slice = blockIdx.x & 63;
#pragma unroll
        for (int j = 0; j < 4; ++j) {
            float s = 0.f, q = 0.f;
#pragma unroll
            for (int i = 0; i < MI; ++i)
#pragma unroll
                for (int e = 0; e < 4; ++e) {
                    float v = acc[i][j][e];
                    s += v; q += v * v;
                }
            s += __shfl_xor(s, 16); s += __shfl_xor(s, 32);
            q += __shfl_xor(q, 16); q += __shfl_xor(q, 32);
            if ((lane >> 4) == 0) {
                int col = n0 + wc + j * 16 + lane;
                atomicAdd(&psum[slice * 1024 + col], s);
                atomicAdd(&psq[slice * 1024 + col], q);
            }
        }
    }
}

// ---------------- layer-0: fused dense (C=3) + gather-reduce + BN stats ----------------
__global__ __launch_bounds__(256)
void k_gather0(const float* __restrict__ x, const float* __restrict__ w0,
               const int* __restrict__ nidx, const float* __restrict__ g,
               _Float16* __restrict__ exth,
               float* __restrict__ psum, float* __restrict__ psq) {
    constexpr int O = 64, VPT = 8, P = 32;
    __shared__ float s_red[P * O];
    __shared__ float q_red[P * O];
    const int tid = threadIdx.x;
    const int pl = tid / VPT, v = tid % VPT;
    int bsw, local;
    swz_batch(blockIdx.x, bsw, local);
    const int bbase = bsw * N_;
    const int p = bbase + local * P + pl;
    float wa[8][3], wd[8][3], sg[8];
#pragma unroll
    for (int e = 0; e < 8; ++e) {
        int o = v * 8 + e;
        float a0 = w0[o * 6], a1 = w0[o * 6 + 1], a2 = w0[o * 6 + 2];
        wa[e][0] = a0; wa[e][1] = a1; wa[e][2] = a2;
        wd[e][0] = w0[o * 6 + 3] - a0;
        wd[e][1] = w0[o * 6 + 4] - a1;
        wd[e][2] = w0[o * 6 + 5] - a2;
        sg[e] = (g[o] >= 0.f) ? 1.f : -1.f;
    }
    float mx[8], sm[8], sq[8];
#pragma unroll
    for (int e = 0; e < 8; ++e) { mx[e] = -3.4e38f; sm[e] = 0.f; sq[e] = 0.f; }
    const int* np = nidx + p * K_;
#pragma unroll 4
    for (int k = 0; k < K_; ++k) {
        int j = bbase + np[k];
        float x0 = x[j * 3], x1 = x[j * 3 + 1], x2 = x[j * 3 + 2];
#pragma unroll
        for (int e = 0; e < 8; ++e) {
            float f = wa[e][0] * x0 + wa[e][1] * x1 + wa[e][2] * x2;
            mx[e] = fmaxf(mx[e], f * sg[e]);
            sm[e] += f;
            sq[e] += f * f;
        }
    }
    float xp0 = x[p * 3], xp1 = x[p * 3 + 1], xp2 = x[p * 3 + 2];
    const float Kf = (float)K_;
    half8v exo;
#pragma unroll
    for (int e = 0; e < 8; ++e) {
        float zf = wd[e][0] * xp0 + wd[e][1] * xp1 + wd[e][2] * xp2;
        exo[e] = (_Float16)(sg[e] * mx[e] + zf);
        s_red[pl * O + v * 8 + e] = sm[e] + Kf * zf;
        q_red[pl * O + v * 8 + e] = sq[e] + 2.f * zf * sm[e] + Kf * zf * zf;
    }
    *(half8v*)&exth[(size_t)p * O + v * 8] = exo;
    __syncthreads();
    int slice = blockIdx.x & 63;
    for (int ch = tid; ch < O; ch += 256) {
        float s = 0.f, q = 0.f;
#pragma unroll
        for (int pp = 0; pp < P; ++pp) { s += s_red[pp * O + ch]; q += q_red[pp * O + ch]; }
        atomicAdd(&psum[slice * 1024 + ch], s);
        atomicAdd(&psq[slice * 1024 + ch], q);
    }
}

// ---------------- gather-reduce + fused BN stats (single extremum, batch-XCD-swizzled) ----------------
template<int O>
__global__ __launch_bounds__(256)
void k_gather(const _Float16* __restrict__ Z, const int* __restrict__ nidx,
              const float* __restrict__ g,
              _Float16* __restrict__ exth,
              float* __restrict__ psum, float* __restrict__ psq) {
    constexpr int VPT = O / 8, P = 256 / VPT;
    __shared__ float s_red[P * O];
    __shared__ float q_red[P * O];
    const int tid = threadIdx.x;
    const int pl = tid / VPT, v = tid % VPT;
    int bsw, local;
    swz_batch(blockIdx.x, bsw, local);
    const int bbase = bsw * N_;
    const int p = bbase + local * P + pl;
    float sg[8];
#pragma unroll
    for (int e = 0; e < 8; ++e) sg[e] = (g[v * 8 + e] >= 0.f) ? 1.f : -1.f;
    float mx[8], sm[8], sq[8];
#pragma unroll
    for (int e = 0; e < 8; ++e) { mx[e] = -3.4e38f; sm[e] = 0.f; sq[e] = 0.f; }
    const int* np = nidx + p * K_;
#pragma unroll 4
    for (int k = 0; k < K_; ++k) {
        int j = np[k];
        half8v z = *(const half8v*)&Z[(size_t)(bbase + j) * (2 * O) + v * 8];
#pragma unroll
        for (int e = 0; e < 8; ++e) {
            float f = (float)z[e];
            mx[e] = fmaxf(mx[e], f * sg[e]);
            sm[e] += f;
            sq[e] += f * f;
        }
    }
    half8v zd = *(const half8v*)&Z[(size_t)p * (2 * O) + O + v * 8];
    const float Kf = (float)K_;
    half8v exo;
#pragma unroll
    for (int e = 0; e < 8; ++e) {
        float zf = (float)zd[e];
        exo[e] = (_Float16)(sg[e] * mx[e] + zf);
        s_red[pl * O + v * 8 + e] = sm[e] + Kf * zf;
        q_red[pl * O + v * 8 + e] = sq[e] + 2.f * zf * sm[e] + Kf * zf * zf;
    }
    *(half8v*)&exth[(size_t)p * O + v * 8] = exo;
    __syncthreads();
    int slice = blockIdx.x & 63;
    for (int ch = tid; ch < O; ch += 256) {
        float s = 0.f, q = 0.f;
#pragma unroll
        for (int pp = 0; pp < P; ++pp) { s += s_red[pp * O + ch]; q += q_red[pp * O + ch]; }
        atomicAdd(&psum[slice * 1024 + ch], s);
        atomicAdd(&psq[slice * 1024 + ch], q);
    }
}

// ---------------- fused finalize + BN-apply (consumer-side finalize, r9/r11-verified) ----------------
template<int O>
__global__ __launch_bounds__(256)
void k_bnfin(const _Float16* __restrict__ exth,
             const float* __restrict__ psum, const float* __restrict__ psq,
             const float* __restrict__ g, const float* __restrict__ b, float cntInv,
             _Float16* __restrict__ cath, int coff) {
    constexpr int NCT = O / 64;                      // channel tiles
    __shared__ float part_s[64][4];
    __shared__ float part_q[64][4];
    __shared__ float scale_s[64], shift_s[64];
    const int tid = threadIdx.x;
    const int ct = blockIdx.x % NCT;
    const int ptile = blockIdx.x / NCT;              // [0,64)
    int bsw, local;
    swz_batch(ptile, bsw, local);                    // local in [0,16)
    const int ch0 = ct * 64;
    {   // phase 1: per-channel slice reduction (4 threads/channel, 16 slices each)
        int lc = tid >> 2, q = tid & 3;
        int ch = ch0 + lc;
        float s = 0.f, qq = 0.f;
        for (int i = q * 16; i < q * 16 + 16; ++i) {
            s += psum[i * 1024 + ch];
            qq += psq[i * 1024 + ch];
        }
        part_s[lc][q] = s; part_q[lc][q] = qq;
    }
    __syncthreads();
    if ((tid & 3) == 0) {
        int lc = tid >> 2;
        float s = part_s[lc][0] + part_s[lc][1] + part_s[lc][2] + part_s[lc][3];
        float qq = part_q[lc][0] + part_q[lc][1] + part_q[lc][2] + part_q[lc][3];
        float m = s * cntInv;
        float v = qq * cntInv - m * m;
        float sc = g[ch0 + lc] * rsqrtf(fmaxf(v, 0.f) + EPSBN);
        scale_s[lc] = sc;
        shift_s[lc] = b[ch0 + lc] - m * sc;
    }
    __syncthreads();
    // phase 2: apply to 128 points x 64 channels
    const int pbase = bsw * N_ + local * 128;
#pragma unroll
    for (int r = 0; r < 4; ++r) {
        int idx = r * 256 + tid;
        int ptl = idx >> 3;                          // [0,128)
        int cb = (idx & 7) * 8;                      // [0,64) in steps of 8
        int p = pbase + ptl;
        half8v hx = *(const half8v*)&exth[(size_t)p * O + ch0 + cb];
        half8v rr;
#pragma unroll
        for (int e = 0; e < 8; ++e) {
            float y = scale_s[cb + e] * (float)hx[e] + shift_s[cb + e];
            rr[e] = (_Float16)(y > 0.f ? y : 0.2f * y);
        }
        *(half8v*)&cath[(size_t)p * 960 + coff + ch0 + cb] = rr;
    }
}

// ---------------- BN+lrelu on Y4 -> fo transposed + pool partials (+in-kernel finalize) ----------------
__global__ __launch_bounds__(256)
void k_feats_out(const _Float16* __restrict__ Y4,
                 const float* __restrict__ psum, const float* __restrict__ psq,
                 const float* __restrict__ g, const float* __restrict__ bv,
                 float* __restrict__ fo,
                 float* __restrict__ pmax, float* __restrict__ psumn) {
    __shared__ float tile[64][65];
    __shared__ float part_s[64][4];
    __shared__ float part_q[64][4];
    __shared__ float scale_s[64], shift_s[64];
    const int tid = threadIdx.x;
    // decode: slot = id&7 -> b = slot>>1, parity = slot&1; nx chosen so (nx>>1)&1 == parity
    const int id = blockIdx.x;
    const int b = (id & 7) >> 1, par = id & 1;
    const int local = id >> 3;                       // [0,256)
    const int cy = local >> 4;                       // [0,16) c-tile
    const int k = local & 15;
    const int nx = ((k >> 1) << 2) | (par << 1) | (k & 1);   // [0,32), slot-parity matched
    const int n0 = nx * 64, c0 = cy * 64;
    // ---- phase 0: finalize BN scale/shift for this 64-channel tile ----
    {
        int lc = tid >> 2, q = tid & 3;
        int ch = c0 + lc;
        float s = 0.f, qq = 0.f;
        for (int i = q * 16; i < q * 16 + 16; ++i) {
            s += psum[i * 1024 + ch];
            qq += psq[i * 1024 + ch];
        }
        part_s[lc][q] = s; part_q[lc][q] = qq;
    }
    __syncthreads();
    if ((tid & 3) == 0) {
        int lc = tid >> 2;
        const float cntInv = 1.f / (B_ * N_);
        float s = part_s[lc][0] + part_s[lc][1] + part_s[lc][2] + part_s[lc][3];
        float qq = part_q[lc][0] + part_q[lc][1] + part_q[lc][2] + part_q[lc][3];
        float m = s * cntInv;
        float v = qq * cntInv - m * m;
        float sc = g[c0 + lc] * rsqrtf(fmaxf(v, 0.f) + EPSBN);
        scale_s[lc] = sc;
        shift_s[lc] = bv[c0 + lc] - m * sc;
    }
    __syncthreads();
    // ---- phase 1: vectorized load + BN + lrelu into LDS transpose tile ----
#pragma unroll
    for (int r = 0; r < 2; ++r) {
        int idx = r * 256 + tid;                 // 512 half8 chunks = 64n x 8 c-groups
        int nl = idx >> 3;
        int c8 = (idx & 7) * 8;
        half8v h = *(const half8v*)&Y4[((size_t)(b * N_ + n0 + nl)) * 1024 + c0 + c8];
#pragma unroll
        for (int e = 0; e < 8; ++e) {
            float y = scale_s[c8 + e] * (float)h[e] + shift_s[c8 + e];
            tile[nl][c8 + e] = y > 0.f ? y : 0.2f * y;
        }
    }
    __syncthreads();
    // ---- phase 2: transposed float4 stores + pool partials ----
#pragma unroll
    for (int r = 0; r < 4; ++r) {
        int idx = r * 256 + tid;                 // 1024 float4 chunks = 64c x 16 n-groups
        int cl = idx >> 4;
        int n4 = (idx & 15) * 4;
        float4 v;
        v.x = tile[n4 + 0][cl];
        v.y = tile[n4 + 1][cl];
        v.z = tile[n4 + 2][cl];
        v.w = tile[n4 + 3][cl];
        *(float4*)&fo[((size_t)(b * 1024 + c0 + cl)) * N_ + n0 + n4] = v;
        float mx = fmaxf(fmaxf(v.x, v.y), fmaxf(v.z, v.w));
        float sm = v.x + v.y + v.z + v.w;
#pragma unroll
        for (int d = 1; d < 16; d <<= 1) {       // reduce the 16-lane group covering 64 n
            mx = fmaxf(mx, __shfl_xor(mx, d));
            sm += __shfl_xor(sm, d);
        }
        if ((tid & 15) == 0) {
            int bc = (b << 10) + c0 + cl;
            pmax[(size_t)bc * 32 + nx] = mx;
            psumn[(size_t)bc * 32 + nx] = sm;
        }
    }
}

// final pool: per (b,c) reduce 32 tile-partials -> z0 (B,2048) = [max | mean]
__global__ void k_pool2(const float* __restrict__ pmax, const float* __restrict__ psumn,
                        float* __restrict__ z0) {
    int bc = blockIdx.x * 8 + (threadIdx.x >> 5);
    int lane = threadIdx.x & 31;
    float mx = pmax[(size_t)bc * 32 + lane];
    float s  = psumn[(size_t)bc * 32 + lane];
#pragma unroll
    for (int d = 1; d < 32; d <<= 1) {
        mx = fmaxf(mx, __shfl_xor(mx, d));
        s += __shfl_xor(s, d);
    }
    if (lane == 0) {
        int b = bc >> 10, c = bc & 1023;
        z0[b * 2048 + c] = mx;
        z0[b * 2048 + 1024 + c] = s * (1.f / N_);
    }
}

// ---------------- FC: one wave per (batch, output) dot product; optional fused batch-BN+lrelu ----------------
__global__ void k_fc(const float* __restrict__ zin, const float* __restrict__ W,
                     const float* __restrict__ bias,
                     const float* __restrict__ gg, const float* __restrict__ gb,
                     int C, int O, float* __restrict__ zout) {
    __shared__ float sh4[4];
    const int b = threadIdx.x >> 6;
    const int lane = threadIdx.x & 63;
    const int o = blockIdx.x;
    const float* wr = W + (size_t)o * C;
    const float* zr = zin + b * C;
    float s = 0.f;
    for (int c = lane * 4; c < C; c += 256) {
        const float4 wv = *(const float4*)&wr[c];
        const float4 zv = *(const float4*)&zr[c];
        s += wv.x * zv.x + wv.y * zv.y + wv.z * zv.z + wv.w * zv.w;
    }
    s += __shfl_xor(s, 1);
    s += __shfl_xor(s, 2);
    s += __shfl_xor(s, 4);
    s += __shfl_xor(s, 8);
    s += __shfl_xor(s, 16);
    s += __shfl_xor(s, 32);
    if (!gg) {
        if (lane == 0) zout[b * O + o] = s + (bias ? bias[o] : 0.f);
        return;
    }
    if (lane == 0) sh4[b] = s + (bias ? bias[o] : 0.f);
    __syncthreads();
    if (threadIdx.x == 0) {
        float v0 = sh4[0], v1 = sh4[1], v2 = sh4[2], v3 = sh4[3];
        float m = 0.25f * (v0 + v1 + v2 + v3);
        float d0 = v0 - m, d1 = v1 - m, d2 = v2 - m, d3 = v3 - m;
        float var = 0.25f * (d0 * d0 + d1 * d1 + d2 * d2 + d3 * d3);
        float sc = gg[o] * rsqrtf(var + EPSBN);
        float shv = gb[o];
        float r0 = sc * d0 + shv, r1 = sc * d1 + shv, r2 = sc * d2 + shv, r3 = sc * d3 + shv;
        zout[o]         = r0 > 0.f ? r0 : 0.2f * r0;
        zout[O + o]     = r1 > 0.f ? r1 : 0.2f * r1;
        zout[2 * O + o] = r2 > 0.f ? r2 : 0.2f * r2;
        zout[3 * O + o] = r3 > 0.f ? r3 : 0.2f * r3;
    }
}

// ---------------- launch ----------------

extern "C" void kernel_launch(void* const* d_in, const int* in_sizes, int n_in,
                              void* d_out, int out_size, void* d_ws, size_t ws_size,
                              hipStream_t stream) {
    const float* x    = (const float*)d_in[0];
    const int*   nidx = (const int*)d_in[1];
    const float* w[5]  = {(const float*)d_in[2], (const float*)d_in[5], (const float*)d_in[8],
                          (const float*)d_in[11], (const float*)d_in[14]};
    const float* g[5]  = {(const float*)d_in[3], (const float*)d_in[6], (const float*)d_in[9],
                          (const float*)d_in[12], (const float*)d_in[15]};
    const float* bb[5] = {(const float*)d_in[4], (const float*)d_in[7], (const float*)d_in[10],
                          (const float*)d_in[13], (const float*)d_in[16]};
    const float* lw1 = (const float*)d_in[17];
    const float* g6  = (const float*)d_in[18];
    const float* b6  = (const float*)d_in[19];
    const float* lw2 = (const float*)d_in[20];
    const float* lb2 = (const float*)d_in[21];
    const float* g7  = (const float*)d_in[22];
    const float* b7  = (const float*)d_in[23];
    const float* lw3 = (const float*)d_in[24];
    const float* lb3 = (const float*)d_in[25];

    float* out = (float*)d_out;
    float* fo  = out + 1024;              // feats (B,1024,N)

    uint8_t* base8 = (uint8_t*)d_ws;
    size_t off = 0;
    auto alloc = [&](size_t bytes) -> void* {
        void* r = base8 + off;
        off += (bytes + 255) & ~(size_t)255;
        return r;
    };
    _Float16* cath = (_Float16*)alloc((size_t)B_ * N_ * 960 * 2);   // 15.7 MB
    _Float16* Z    = (_Float16*)alloc((size_t)8192 * 1024 * 2);     // 16.8 MB
    _Float16* exth = (_Float16*)alloc((size_t)8192 * 512 * 2);      // 8.4 MB
    _Float16* Y4   = (_Float16*)alloc((size_t)8192 * 1024 * 2);     // 16.8 MB
    _Float16* W2h1 = (_Float16*)alloc((size_t)256 * 64 * 2);
    _Float16* W2h2 = (_Float16*)alloc((size_t)512 * 128 * 2);
    _Float16* W2h3 = (_Float16*)alloc((size_t)1024 * 256 * 2);
    _Float16* w4h  = (_Float16*)alloc((size_t)1024 * 960 * 2);
    float* psumall = (float*)alloc((size_t)5 * 131072 * 4);         // 2.6 MB, 5 regions
    float* pmax  = (float*)alloc((size_t)4096 * 32 * 4);            // 512 KB
    float* psumn = (float*)alloc((size_t)4096 * 32 * 4);            // 512 KB
    float* z0    = (float*)alloc(8192 * 4);
    float* z1    = (float*)alloc(4096 * 4);
    float* z2    = (float*)alloc(2048 * 4);
    (void)ws_size; (void)in_sizes; (void)n_in; (void)out_size;

    auto psumR = [&](int r) { return psumall + (size_t)r * 131072; };
    auto psqR  = [&](int r) { return psumall + (size_t)r * 131072 + 65536; };

    // one upfront zero of all stat regions + one fused weight-prep launch
    hipMemsetAsync(psumall, 0, (size_t)5 * 131072 * 4, stream);
    k_prep_all<<<(8192 + 32768 + 131072 + 983040 + 255) / 256, 256, 0, stream>>>(
        w[1], w[2], w[3], w[4], W2h1, W2h2, W2h3, w4h);

    const float invK = 1.f / (B_ * N_ * K_);

    // ---- layer 0 (C=3 -> O=64): fused dense + gather, then fused finalize+BN ----
    k_gather0<<<256, 256, 0, stream>>>(x, w[0], nidx, g[0], exth, psumR(0), psqR(0));
    k_bnfin<64><<<64, 256, 0, stream>>>(exth, psumR(0), psqR(0), g[0], bb[0], invK, cath, 0);

    // ---- layers 1-3: dense MFMA GEMM + fused gather + finalize+BN ----
    // BM=64 only where CU coverage is fractional (G1, G2); BM=128 for the big GEMMs (r12).
    k_gemm<false, 64><<<dim3(128, 2), 256, 0, stream>>>(cath + 0, 960, W2h1, 64,
                                                        Z, 256, nullptr, nullptr);
    k_gather<128><<<512, 256, 0, stream>>>(Z, nidx, g[1], exth, psumR(1), psqR(1));
    k_bnfin<128><<<128, 256, 0, stream>>>(exth, psumR(1), psqR(1), g[1], bb[1], invK, cath, 64);

    k_gemm<false, 64><<<dim3(128, 4), 256, 0, stream>>>(cath + 64, 960, W2h2, 128,
                                                        Z, 512, nullptr, nullptr);
    k_gather<256><<<1024, 256, 0, stream>>>(Z, nidx, g[2], exth, psumR(2), psqR(2));
    k_bnfin<256><<<256, 256, 0, stream>>>(exth, psumR(2), psqR(2), g[2], bb[2], invK, cath, 192);

    k_gemm<false, 128><<<dim3(64, 8), 256, 0, stream>>>(cath + 192, 960, W2h3, 256,
                                                        Z, 1024, nullptr, nullptr);
    k_gather<512><<<2048, 256, 0, stream>>>(Z, nidx, g[3], exth, psumR(3), psqR(3));
    k_bnfin<512><<<512, 256, 0, stream>>>(exth, psumR(3), psqR(3), g[3], bb[3], invK, cath, 448);

    // ---- feats = lrelu(bn(w4 @ cat)); finalize fused into feats_out's phase 0 ----
    k_gemm<true, 128><<<dim3(64, 8), 256, 0, stream>>>(cath, 960, w4h, 960, Y4, 1024,
                                                       psumR(4), psqR(4));
    k_feats_out<<<2048, 256, 0, stream>>>(Y4, psumR(4), psqR(4), g[4], bb[4], fo, pmax, psumn);
    k_pool2<<<512, 256, 0, stream>>>(pmax, psumn, z0);

    // ---- FC head (BN fused into FC blocks) ----
    k_fc<<<1024, 256, 0, stream>>>(z0, lw1, nullptr, g6, b6, 2048, 1024, z1);
    k_fc<<<512, 256, 0, stream>>>(z1, lw2, lb2, g7, b7, 1024, 512, z2);
    k_fc<<<256, 256, 0, stream>>>(z2, lw3, lb3, nullptr, nullptr, 512, 256, out);
}